// Round 1
// baseline (1171.416 us; speedup 1.0000x reference)
//
#include <hip/hip_runtime.h>
#include <math.h>

#define BB 8
#define CC 256
#define NN 1024
#define HH 8
#define FF 96            // (C/H)*3
#define SZ 6291456L      // B*C*3*N
#define BH 64
#define MC 128           // attention m-chunk
#define VN_EPS 1e-6f
#define LN_EPS 1e-5f
#define BN_EPS 1e-5f

// ---------------------------------------------------------------- u = eps*b/||b||
__global__ __launch_bounds__(256) void k_compute_u(
    const float* __restrict__ b0, const float* __restrict__ b1,
    const float* __restrict__ b2, const float* __restrict__ b3,
    const float* __restrict__ b4, const float* __restrict__ b5,
    float* __restrict__ uall)
{
    const float* bs[6] = {b0, b1, b2, b3, b4, b5};
    const float* bptr = bs[blockIdx.x];
    const int co = threadIdx.x;
    const float v0 = bptr[co*3+0], v1 = bptr[co*3+1], v2 = bptr[co*3+2];
    const float inv = rsqrtf(v0*v0 + v1*v1 + v2*v2);
    float* u = uall + blockIdx.x*768 + co*3;
    u[0] = VN_EPS*v0*inv; u[1] = VN_EPS*v1*inv; u[2] = VN_EPS*v2*inv;
}

// ---------------------------------------------------------------- GEMM: Out[m,j] = alpha * sum_k A[k,m]*B[k,j] (+U[m*3 + (j>>10)])
// A: [K, lda] row-major (column index m0+m), B: [K, ldb], Out: [*, ldo]
__global__ __launch_bounds__(256) void k_gemm(
    const float* __restrict__ A, const float* __restrict__ Bm,
    const float* __restrict__ U, float* __restrict__ Out,
    int K, int lda, int ldb, int ldo, int m0,
    long sA, long sB, long sO, float alpha)
{
    __shared__ float As[16][68];
    __shared__ float Bs[16][68];
    const int tx = threadIdx.x, ty = threadIdx.y;
    const int t  = ty*16 + tx;
    const int lr = t >> 4;          // 0..15
    const int lc = (t & 15) << 2;   // 0..60
    A   += (long)blockIdx.z * sA;
    Bm  += (long)blockIdx.z * sB;
    Out += (long)blockIdx.z * sO;
    const int bm = blockIdx.y << 6;
    const int bj = blockIdx.x << 6;
    float acc[4][4] = {};
    for (int k0 = 0; k0 < K; k0 += 16) {
        const float4 av = *reinterpret_cast<const float4*>(A  + (long)(k0+lr)*lda + m0 + bm + lc);
        const float4 bv = *reinterpret_cast<const float4*>(Bm + (long)(k0+lr)*ldb + bj + lc);
        *reinterpret_cast<float4*>(&As[lr][lc]) = av;
        *reinterpret_cast<float4*>(&Bs[lr][lc]) = bv;
        __syncthreads();
        #pragma unroll
        for (int kk = 0; kk < 16; ++kk) {
            const float4 a  = *reinterpret_cast<const float4*>(&As[kk][ty << 2]);
            const float4 b  = *reinterpret_cast<const float4*>(&Bs[kk][tx << 2]);
            const float a4[4] = {a.x, a.y, a.z, a.w};
            const float b4[4] = {b.x, b.y, b.z, b.w};
            #pragma unroll
            for (int i = 0; i < 4; ++i)
                #pragma unroll
                for (int j = 0; j < 4; ++j)
                    acc[i][j] += a4[i] * b4[j];
        }
        __syncthreads();
    }
    #pragma unroll
    for (int i = 0; i < 4; ++i) {
        const int row = bm + (ty << 2) + i;
        const int col = bj + (tx << 2);
        float ub = 0.0f;
        if (U) ub = U[row*3 + (col >> 10)];
        float4 o;
        o.x = acc[i][0]*alpha + ub;
        o.y = acc[i][1]*alpha + ub;
        o.z = acc[i][2]*alpha + ub;
        o.w = acc[i][3]*alpha + ub;
        *reinterpret_cast<float4*>(Out + (long)row*ldo + col) = o;
    }
}

// ---------------------------------------------------------------- softmax over rows of 1024
__global__ __launch_bounds__(256) void k_softmax(float* __restrict__ S)
{
    float* p = S + (long)blockIdx.x * 1024;
    const int t = threadIdx.x;
    float4 v = *reinterpret_cast<const float4*>(p + (t << 2));
    float m = fmaxf(fmaxf(v.x, v.y), fmaxf(v.z, v.w));
    #pragma unroll
    for (int off = 32; off > 0; off >>= 1)
        m = fmaxf(m, __shfl_xor(m, off));
    __shared__ float red[4];
    const int wave = t >> 6, lane = t & 63;
    if (lane == 0) red[wave] = m;
    __syncthreads();
    m = fmaxf(fmaxf(red[0], red[1]), fmaxf(red[2], red[3]));
    v.x = __expf(v.x - m); v.y = __expf(v.y - m);
    v.z = __expf(v.z - m); v.w = __expf(v.w - m);
    float s = v.x + v.y + v.z + v.w;
    #pragma unroll
    for (int off = 32; off > 0; off >>= 1)
        s += __shfl_xor(s, off);
    __shared__ float red2[4];
    if (lane == 0) red2[wave] = s;
    __syncthreads();
    s = red2[0] + red2[1] + red2[2] + red2[3];
    const float inv = 1.0f / s;
    v.x *= inv; v.y *= inv; v.z *= inv; v.w *= inv;
    *reinterpret_cast<float4*>(p + (t << 2)) = v;
}

// ---------------------------------------------------------------- PV: Out[f, mcBase+m] = sum_n Z[f,n]*P[m,n]
__global__ __launch_bounds__(128) void k_pv(
    const float* __restrict__ Z, const float* __restrict__ P,
    float* __restrict__ Out, int mcBase)
{
    __shared__ float Zs[32][36];   // [k][f]
    __shared__ float Ps[32][68];   // [k][m]
    const int bh = blockIdx.z;
    Z   += (long)bh * 98304;   // 96*1024
    P   += (long)bh * 131072;  // MC*1024
    Out += (long)bh * 98304;
    const int bf = blockIdx.y << 5;
    const int bm = blockIdx.x << 6;
    const int tx = threadIdx.x, ty = threadIdx.y;   // (16, 8)
    const int t  = ty*16 + tx;
    const int lr = t >> 3;          // 0..15
    const int lc = (t & 7) << 2;    // 0..28
    float acc[4][4] = {};
    for (int k0 = 0; k0 < 1024; k0 += 32) {
        const float4 z0 = *reinterpret_cast<const float4*>(Z + (long)(bf+lr   )*1024 + k0 + lc);
        const float4 z1 = *reinterpret_cast<const float4*>(Z + (long)(bf+lr+16)*1024 + k0 + lc);
        Zs[lc+0][lr]    = z0.x; Zs[lc+1][lr]    = z0.y; Zs[lc+2][lr]    = z0.z; Zs[lc+3][lr]    = z0.w;
        Zs[lc+0][lr+16] = z1.x; Zs[lc+1][lr+16] = z1.y; Zs[lc+2][lr+16] = z1.z; Zs[lc+3][lr+16] = z1.w;
        const float4 p0 = *reinterpret_cast<const float4*>(P + (long)(bm+lr   )*1024 + k0 + lc);
        const float4 p1 = *reinterpret_cast<const float4*>(P + (long)(bm+lr+16)*1024 + k0 + lc);
        const float4 p2 = *reinterpret_cast<const float4*>(P + (long)(bm+lr+32)*1024 + k0 + lc);
        const float4 p3 = *reinterpret_cast<const float4*>(P + (long)(bm+lr+48)*1024 + k0 + lc);
        Ps[lc+0][lr]    = p0.x; Ps[lc+1][lr]    = p0.y; Ps[lc+2][lr]    = p0.z; Ps[lc+3][lr]    = p0.w;
        Ps[lc+0][lr+16] = p1.x; Ps[lc+1][lr+16] = p1.y; Ps[lc+2][lr+16] = p1.z; Ps[lc+3][lr+16] = p1.w;
        Ps[lc+0][lr+32] = p2.x; Ps[lc+1][lr+32] = p2.y; Ps[lc+2][lr+32] = p2.z; Ps[lc+3][lr+32] = p2.w;
        Ps[lc+0][lr+48] = p3.x; Ps[lc+1][lr+48] = p3.y; Ps[lc+2][lr+48] = p3.z; Ps[lc+3][lr+48] = p3.w;
        __syncthreads();
        #pragma unroll
        for (int kk = 0; kk < 32; ++kk) {
            const float4 a = *reinterpret_cast<const float4*>(&Zs[kk][ty << 2]);
            const float4 b = *reinterpret_cast<const float4*>(&Ps[kk][tx << 2]);
            const float a4[4] = {a.x, a.y, a.z, a.w};
            const float b4[4] = {b.x, b.y, b.z, b.w};
            #pragma unroll
            for (int i = 0; i < 4; ++i)
                #pragma unroll
                for (int j = 0; j < 4; ++j)
                    acc[i][j] += a4[i] * b4[j];
        }
        __syncthreads();
    }
    #pragma unroll
    for (int i = 0; i < 4; ++i) {
        const int f = bf + (ty << 2) + i;
        float4 o;
        o.x = acc[i][0]; o.y = acc[i][1]; o.z = acc[i][2]; o.w = acc[i][3];
        *reinterpret_cast<float4*>(Out + (long)f*1024 + mcBase + bm + (tx << 2)) = o;
    }
}

// ---------------------------------------------------------------- VN LayerNorm (+ optional residual)
__global__ __launch_bounds__(256) void k_vnln(
    const float* __restrict__ X, const float* __restrict__ Res,
    const float* __restrict__ g, const float* __restrict__ be,
    float* __restrict__ Out)
{
    const int b  = blockIdx.x >> 5;
    const int n  = ((blockIdx.x & 31) << 5) + threadIdx.x;
    const int ty = threadIdx.y;        // 0..7
    const long bbase = (long)b * (CC*3*NN);
    float sum = 0.0f, sq = 0.0f;
    for (int ci = 0; ci < 32; ++ci) {
        const int c = (ty << 5) + ci;
        const long base = bbase + (long)c*3072 + n;
        const float x0 = X[base], x1 = X[base+1024], x2 = X[base+2048];
        const float nr = sqrtf(x0*x0 + x1*x1 + x2*x2) + VN_EPS;
        sum += nr; sq += nr*nr;
    }
    __shared__ float s_sum[8][32], s_sq[8][32];
    s_sum[ty][threadIdx.x] = sum; s_sq[ty][threadIdx.x] = sq;
    __syncthreads();
    __shared__ float s_mu[32], s_rs[32];
    if (ty == 0) {
        float S = 0.0f, Q = 0.0f;
        #pragma unroll
        for (int w = 0; w < 8; ++w) { S += s_sum[w][threadIdx.x]; Q += s_sq[w][threadIdx.x]; }
        const float mu = S / 256.0f;
        s_mu[threadIdx.x] = mu;
        s_rs[threadIdx.x] = rsqrtf(Q / 256.0f - mu*mu + LN_EPS);
    }
    __syncthreads();
    const float mu = s_mu[threadIdx.x], rstd = s_rs[threadIdx.x];
    for (int ci = 0; ci < 32; ++ci) {
        const int c = (ty << 5) + ci;
        const long base = bbase + (long)c*3072 + n;
        const float x0 = X[base], x1 = X[base+1024], x2 = X[base+2048];
        const float nr = sqrtf(x0*x0 + x1*x1 + x2*x2) + VN_EPS;
        const float ln = (nr - mu) * rstd * g[c] + be[c];
        const float s  = ln / nr;
        float o0 = x0*s, o1 = x1*s, o2 = x2*s;
        if (Res) { o0 += Res[base]; o1 += Res[base+1024]; o2 += Res[base+2048]; }
        Out[base] = o0; Out[base+1024] = o1; Out[base+2048] = o2;
    }
}

// ---------------------------------------------------------------- BatchNorm stats (per channel over B,N)
__global__ __launch_bounds__(256) void k_bn_stats(
    const float* __restrict__ X, float* __restrict__ nb,
    float* __restrict__ mean, float* __restrict__ rstd)
{
    const int c = blockIdx.x;
    const int t = threadIdx.x;
    float sum = 0.0f, sq = 0.0f;
    for (int b = 0; b < BB; ++b) {
        const long rowbase = ((long)(b*CC + c)) * 3072;
        const long nbase   = ((long)(b*CC + c)) << 10;
        for (int n0 = 0; n0 < NN; n0 += 256) {
            const int n = n0 + t;
            const float x0 = X[rowbase + n], x1 = X[rowbase + 1024 + n], x2 = X[rowbase + 2048 + n];
            const float nr = sqrtf(x0*x0 + x1*x1 + x2*x2) + VN_EPS;
            nb[nbase + n] = nr;
            sum += nr; sq += nr*nr;
        }
    }
    #pragma unroll
    for (int off = 32; off > 0; off >>= 1) {
        sum += __shfl_xor(sum, off);
        sq  += __shfl_xor(sq,  off);
    }
    __shared__ float rs[4], rq[4];
    if ((t & 63) == 0) { rs[t >> 6] = sum; rq[t >> 6] = sq; }
    __syncthreads();
    if (t == 0) {
        const float S = rs[0]+rs[1]+rs[2]+rs[3];
        const float Q = rq[0]+rq[1]+rq[2]+rq[3];
        const float mu = S / 8192.0f;
        mean[c] = mu;
        rstd[c] = rsqrtf(Q / 8192.0f - mu*mu + BN_EPS);
    }
}

// ---------------------------------------------------------------- BatchNorm apply (in place)
__global__ __launch_bounds__(256) void k_bn_apply(
    float* __restrict__ X, const float* __restrict__ nb,
    const float* __restrict__ mean, const float* __restrict__ rstd,
    const float* __restrict__ g, const float* __restrict__ be)
{
    const long i = (long)blockIdx.x * 256 + threadIdx.x;   // < B*C*N
    const int  n  = (int)(i & 1023);
    const long bc = i >> 10;
    const int  c  = (int)(bc & 255);
    const float nr = nb[i];
    const float bn = (nr - mean[c]) * rstd[c] * g[c] + be[c];
    const float s  = bn / nr;
    const long base = bc * 3072 + n;
    X[base]      *= s;
    X[base+1024] *= s;
    X[base+2048] *= s;
}

// ---------------------------------------------------------------- VN leaky relu (slope 0), in place
__global__ __launch_bounds__(256) void k_leaky(
    float* __restrict__ X, const float* __restrict__ Dd)
{
    const long i = (long)blockIdx.x * 256 + threadIdx.x;   // < B*C*N
    const long base = (i >> 10) * 3072 + (i & 1023);
    const float x0 = X[base], x1 = X[base+1024], x2 = X[base+2048];
    const float d0 = Dd[base], d1 = Dd[base+1024], d2 = Dd[base+2048];
    const float dot = x0*d0 + x1*d1 + x2*d2;
    if (dot < 0.0f) {
        const float f = dot / (d0*d0 + d1*d1 + d2*d2 + VN_EPS);
        X[base]      = x0 - f*d0;
        X[base+1024] = x1 - f*d1;
        X[base+2048] = x2 - f*d2;
    }
}

// ================================================================ launch
extern "C" void kernel_launch(void* const* d_in, const int* in_sizes, int n_in,
                              void* d_out, int out_size, void* d_ws, size_t ws_size,
                              hipStream_t stream)
{
    const float* x    = (const float*)d_in[0];
    const float* Wq   = (const float*)d_in[1];
    const float* bq   = (const float*)d_in[2];
    const float* Wk   = (const float*)d_in[3];
    const float* bk   = (const float*)d_in[4];
    const float* Wz   = (const float*)d_in[5];
    const float* bz   = (const float*)d_in[6];
    const float* Wo   = (const float*)d_in[7];
    const float* bo   = (const float*)d_in[8];
    const float* ln1g = (const float*)d_in[9];
    const float* ln1b = (const float*)d_in[10];
    const float* Wm1  = (const float*)d_in[11];
    const float* bm1  = (const float*)d_in[12];
    const float* bng  = (const float*)d_in[13];
    const float* bnb  = (const float*)d_in[14];
    const float* Wr   = (const float*)d_in[15];
    const float* Wm2  = (const float*)d_in[16];
    const float* bm2  = (const float*)d_in[17];
    const float* ln2g = (const float*)d_in[18];
    const float* ln2b = (const float*)d_in[19];
    float* out = (float*)d_out;

    float* ws = (float*)d_ws;
    float* B0 = ws;                       // q -> y_proj -> d
    float* B1 = ws + SZ;                  // k -> y(identity)
    float* B2 = ws + 2*SZ;                // z -> h
    float* B3 = out;                      // attn_out -> h2 (d_out doubles as scratch)
    float* Sbuf = ws + 3*SZ;              // 64*128*1024 floats
    float* nb   = Sbuf + (long)BH*MC*1024;// B*C*N floats
    float* mean = nb + (long)BB*CC*NN;
    float* rstd = mean + 256;
    float* uall = rstd + 256;             // 6 * 256*3

    const dim3 blk(16, 16);
    const long sX = (long)CC*3*NN;        // 786432
    const float isq = 0.10206207261596575f;  // 1/sqrt(96)

    k_compute_u<<<6, 256, 0, stream>>>(bq, bk, bz, bo, bm1, bm2, uall);

    // q, k, z projections
    k_gemm<<<dim3(48,4,BB), blk, 0, stream>>>(Wq, x, uall+0*768, B0, 256,256,3072,3072,0, 0L,sX,sX, 1.0f);
    k_gemm<<<dim3(48,4,BB), blk, 0, stream>>>(Wk, x, uall+1*768, B1, 256,256,3072,3072,0, 0L,sX,sX, 1.0f);
    k_gemm<<<dim3(48,4,BB), blk, 0, stream>>>(Wz, x, uall+2*768, B2, 256,256,3072,3072,0, 0L,sX,sX, 1.0f);

    // attention, chunked over M
    for (int mc = 0; mc < NN/MC; ++mc) {
        k_gemm<<<dim3(16,2,BH), blk, 0, stream>>>(B0, B1, nullptr, Sbuf,
                                                  96,1024,1024,1024, mc*MC,
                                                  98304L, 98304L, 131072L, isq);
        k_softmax<<<BH*MC, 256, 0, stream>>>(Sbuf);
        k_pv<<<dim3(2,3,BH), dim3(16,8), 0, stream>>>(B2, Sbuf, B3, mc*MC);
    }

    // out projection, LN1 + residual(x)
    k_gemm<<<dim3(48,4,BB), blk, 0, stream>>>(Wo, B3, uall+3*768, B0, 256,256,3072,3072,0, 0L,sX,sX, 1.0f);
    k_vnln<<<256, dim3(32,8), 0, stream>>>(B0, x, ln1g, ln1b, B1);

    // MLP: h = Wm1(y); BN; leaky(Wr); h2 = Wm2; LN2 + residual(y)
    k_gemm<<<dim3(48,4,BB), blk, 0, stream>>>(Wm1, B1, uall+4*768, B2, 256,256,3072,3072,0, 0L,sX,sX, 1.0f);
    k_bn_stats<<<256, 256, 0, stream>>>(B2, nb, mean, rstd);
    k_bn_apply<<<8192, 256, 0, stream>>>(B2, nb, mean, rstd, bng, bnb);
    k_gemm<<<dim3(48,4,BB), blk, 0, stream>>>(Wr, B2, nullptr, B0, 256,256,3072,3072,0, 0L,sX,sX, 1.0f);
    k_leaky<<<8192, 256, 0, stream>>>(B2, B0);
    k_gemm<<<dim3(48,4,BB), blk, 0, stream>>>(Wm2, B2, uall+5*768, B3, 256,256,3072,3072,0, 0L,sX,sX, 1.0f);
    k_vnln<<<256, dim3(32,8), 0, stream>>>(B3, B1, ln2g, ln2b, out);
}

// Round 7
// 922.903 us; speedup vs baseline: 1.2693x; 1.2693x over previous
//
#include <hip/hip_runtime.h>
#include <math.h>

typedef __attribute__((ext_vector_type(8))) short bf16x8;
typedef __attribute__((ext_vector_type(4))) float f32x4;
typedef unsigned short u16;
typedef __attribute__((ext_vector_type(4))) unsigned short u16x4;
typedef __attribute__((ext_vector_type(8))) unsigned short u16x8;

#define VN_EPS 1e-6f
#define LN_EPS 1e-5f
#define BN_EPS 1e-5f
#define ISQ 0.10206207261596575f

__device__ __forceinline__ u16 f2bf(float f) {
    unsigned u = __builtin_bit_cast(unsigned, f);
    return (u16)((u + 0x7FFFu + ((u >> 16) & 1u)) >> 16);
}
__device__ __forceinline__ float bf2f(u16 h) {
    unsigned u = ((unsigned)h) << 16;
    return __builtin_bit_cast(float, u);
}

// ---------------------------------------------------------------- u = eps*b/||b||
__global__ __launch_bounds__(256) void k_u(
    const float* __restrict__ b0, const float* __restrict__ b1,
    const float* __restrict__ b2, const float* __restrict__ b3,
    const float* __restrict__ b4, const float* __restrict__ b5,
    float* __restrict__ uall)
{
    const float* bs[6] = {b0, b1, b2, b3, b4, b5};
    const float* bp = bs[blockIdx.x];
    const int co = threadIdx.x;
    const float v0 = bp[co*3+0], v1 = bp[co*3+1], v2 = bp[co*3+2];
    const float inv = rsqrtf(v0*v0 + v1*v1 + v2*v2);
    float* u = uall + blockIdx.x*768 + co*3;
    u[0] = VN_EPS*v0*inv; u[1] = VN_EPS*v1*inv; u[2] = VN_EPS*v2*inv;
}

// ---------------------------------------------------------------- W f32 [i][o] -> Wt hi/lo bf16 [o][i]
__global__ __launch_bounds__(256) void k_wtrans(
    const float* __restrict__ w0, const float* __restrict__ w1,
    const float* __restrict__ w2, const float* __restrict__ w3,
    const float* __restrict__ w4, const float* __restrict__ w5,
    const float* __restrict__ w6, u16* __restrict__ wth, u16* __restrict__ wtl)
{
    const int wi = blockIdx.z;
    const float* W = (wi==0)?w0:(wi==1)?w1:(wi==2)?w2:(wi==3)?w3:(wi==4)?w4:(wi==5)?w5:w6;
    u16* WtH = wth + (long)wi*65536;
    u16* WtL = wtl + (long)wi*65536;
    const int i0 = blockIdx.y*64, o0 = blockIdx.x*64;
    __shared__ float st[64][67];
    const int t = threadIdx.x, q = t >> 6, lane = t & 63;
    for (int j = 0; j < 16; ++j) {
        const int i = q*16 + j;
        st[i][lane] = W[(i0 + i)*256 + o0 + lane];
    }
    __syncthreads();
    for (int j = 0; j < 16; ++j) {
        const int o = q*16 + j;
        const float v = st[lane][o];
        const u16 hi = f2bf(v);
        WtH[(o0 + o)*256 + i0 + lane] = hi;
        WtL[(o0 + o)*256 + i0 + lane] = f2bf(v - bf2f(hi));
    }
}

// ---------------------------------------------------------------- split-bf16 channel GEMM
// Out[b][co][d][n] = sum_i W[i][co]*X[b][i][d][n] (+U[co*3+d])
// MODE 0: f32 original layout. MODE 1: hi/lo original layout (z).
// MODE 2: hi/lo head-major [b*8+h][n][f'], f' = d*32+ch (q/k).
template<int MODE>
__global__ __launch_bounds__(256) void k_cgemm(
    const float* __restrict__ X, const u16* __restrict__ WtH, const u16* __restrict__ WtL,
    const float* __restrict__ U,
    float* __restrict__ OutF, u16* __restrict__ OutH, u16* __restrict__ OutL)
{
    __shared__ u16 sh[32768];   // hi plane [0,16384), lo plane [16384,32768)
    const int tid = threadIdx.x;
    const int b = blockIdx.z / 3, d = blockIdx.z % 3;
    const int n0 = blockIdx.x * 64;
    const int co0 = blockIdx.y * 64;

    // stage X[i 256][n 64] -> sh[n][i] hi/lo bf16, XOR-swizzled 16B slots
    {
        const int tn = (tid & 15) * 4;
        const int ti = (tid >> 4) * 4;
        #pragma unroll
        for (int it = 0; it < 4; ++it) {
            const int i_l = it*64 + ti;                         // multiple of 4
            const long rb = (((long)(b*256 + i_l))*3 + d)*1024 + n0 + tn;
            const float4 r0 = *(const float4*)&X[rb];
            const float4 r1 = *(const float4*)&X[rb + 3072];
            const float4 r2 = *(const float4*)&X[rb + 6144];
            const float4 r3 = *(const float4*)&X[rb + 9216];
            const float vals[4][4] = {
                {r0.x, r1.x, r2.x, r3.x},
                {r0.y, r1.y, r2.y, r3.y},
                {r0.z, r1.z, r2.z, r3.z},
                {r0.w, r1.w, r2.w, r3.w}};
            #pragma unroll
            for (int j = 0; j < 4; ++j) {
                const int n = tn + j;
                u16x4 hv, lv;
                #pragma unroll
                for (int e = 0; e < 4; ++e) {
                    const float v = vals[j][e];
                    const u16 hi = f2bf(v);
                    hv[e] = hi;
                    lv[e] = f2bf(v - bf2f(hi));
                }
                const int slot = i_l >> 3;
                const int idx = n*256 + ((((slot ^ (n & 7)) << 3)) | (i_l & 4));
                *(u16x4*)&sh[idx] = hv;
                *(u16x4*)&sh[16384 + idx] = lv;
            }
        }
    }
    __syncthreads();

    const int w = tid >> 6, l = tid & 63;
    const int lr = l & 15, lg = l >> 4;

    f32x4 zero = {0.f, 0.f, 0.f, 0.f};
    f32x4 acc[4] = {zero, zero, zero, zero};

    const long arow = (long)(co0 + w*16 + lr)*256 + lg*8;
    #pragma unroll
    for (int s = 0; s < 8; ++s) {
        const bf16x8 ah = *(const bf16x8*)(WtH + arow + s*32);
        const bf16x8 al = *(const bf16x8*)(WtL + arow + s*32);
        #pragma unroll
        for (int ni = 0; ni < 4; ++ni) {
            const int row = ni*16 + lr;
            const int slot = s*4 + lg;
            const int idx = row*256 + ((slot ^ (row & 7)) << 3);
            const bf16x8 bh_ = *(const bf16x8*)&sh[idx];
            const bf16x8 bl_ = *(const bf16x8*)&sh[16384 + idx];
            acc[ni] = __builtin_amdgcn_mfma_f32_16x16x32_bf16(ah, bh_, acc[ni], 0, 0, 0);
            acc[ni] = __builtin_amdgcn_mfma_f32_16x16x32_bf16(ah, bl_, acc[ni], 0, 0, 0);
            acc[ni] = __builtin_amdgcn_mfma_f32_16x16x32_bf16(al, bh_, acc[ni], 0, 0, 0);
        }
    }

    if constexpr (MODE == 0) {
        #pragma unroll
        for (int ni = 0; ni < 4; ++ni)
            #pragma unroll
            for (int r = 0; r < 4; ++r) {
                const int co = co0 + w*16 + lg*4 + r;
                const int nn = n0 + ni*16 + lr;
                float v = acc[ni][r];
                if (U) v += U[co*3 + d];
                OutF[(((long)(b*256 + co))*3 + d)*1024 + nn] = v;
            }
    } else if constexpr (MODE == 1) {
        #pragma unroll
        for (int ni = 0; ni < 4; ++ni)
            #pragma unroll
            for (int r = 0; r < 4; ++r) {
                const int co = co0 + w*16 + lg*4 + r;
                const int nn = n0 + ni*16 + lr;
                float v = acc[ni][r] + U[co*3 + d];
                const long idx = (((long)(b*256 + co))*3 + d)*1024 + nn;
                const u16 hi = f2bf(v);
                OutH[idx] = hi;
                OutL[idx] = f2bf(v - bf2f(hi));
            }
    } else {
        __syncthreads();                 // sh staging dead; reuse for restage
        u16* olh = sh;                   // [64 co][66 n]
        u16* oll = sh + 8448;
        #pragma unroll
        for (int ni = 0; ni < 4; ++ni)
            #pragma unroll
            for (int r = 0; r < 4; ++r) {
                const int co_l = w*16 + lg*4 + r;
                float v = acc[ni][r] + U[(co0 + co_l)*3 + d];
                const u16 hi = f2bf(v);
                olh[co_l*66 + ni*16 + lr] = hi;
                oll[co_l*66 + ni*16 + lr] = f2bf(v - bf2f(hi));
            }
        __syncthreads();
        const int n_l = tid & 63, grp = tid >> 6;
        const int h = (co0 >> 5) + (grp >> 1);
        const long base = ((long)(b*8 + h)*1024 + n0 + n_l)*96 + d*32 + (grp & 1)*16;
        u16x8 v0h, v1h, v0l, v1l;
        #pragma unroll
        for (int p = 0; p < 8; ++p) {
            v0h[p] = olh[(grp*16 + p)*66 + n_l];
            v1h[p] = olh[(grp*16 + 8 + p)*66 + n_l];
            v0l[p] = oll[(grp*16 + p)*66 + n_l];
            v1l[p] = oll[(grp*16 + 8 + p)*66 + n_l];
        }
        *(u16x8*)&OutH[base]     = v0h;
        *(u16x8*)&OutH[base + 8] = v1h;
        *(u16x8*)&OutL[base]     = v0l;
        *(u16x8*)&OutL[base + 8] = v1l;
    }
}

// ---------------------------------------------------------------- scores: S[m][n] = isq * sum_f q[m][f]*k[n][f]
__global__ __launch_bounds__(256) void k_scores(
    const u16* __restrict__ Qh, const u16* __restrict__ Ql,
    const u16* __restrict__ Kh, const u16* __restrict__ Kl,
    float* __restrict__ Sb, int mc)
{
    const int bh = blockIdx.z;
    const int n0 = blockIdx.x * 64;
    const int tid = threadIdx.x;
    const int w = tid >> 6, l = tid & 63, lr = l & 15, lg = l >> 4;
    const int mrow = mc*128 + blockIdx.y*64 + w*16 + lr;
    f32x4 zero = {0.f, 0.f, 0.f, 0.f};
    f32x4 acc[4] = {zero, zero, zero, zero};
    const long abase = ((long)bh*1024 + mrow)*96 + lg*8;
    #pragma unroll
    for (int s = 0; s < 3; ++s) {
        const bf16x8 ah = *(const bf16x8*)(Qh + abase + s*32);
        const bf16x8 al = *(const bf16x8*)(Ql + abase + s*32);
        #pragma unroll
        for (int ni = 0; ni < 4; ++ni) {
            const long bbase = ((long)bh*1024 + n0 + ni*16 + lr)*96 + s*32 + lg*8;
            const bf16x8 bh_ = *(const bf16x8*)(Kh + bbase);
            const bf16x8 bl_ = *(const bf16x8*)(Kl + bbase);
            acc[ni] = __builtin_amdgcn_mfma_f32_16x16x32_bf16(ah, bh_, acc[ni], 0, 0, 0);
            acc[ni] = __builtin_amdgcn_mfma_f32_16x16x32_bf16(ah, bl_, acc[ni], 0, 0, 0);
            acc[ni] = __builtin_amdgcn_mfma_f32_16x16x32_bf16(al, bh_, acc[ni], 0, 0, 0);
        }
    }
    #pragma unroll
    for (int ni = 0; ni < 4; ++ni)
        #pragma unroll
        for (int r = 0; r < 4; ++r) {
            const int m_c = blockIdx.y*64 + w*16 + lg*4 + r;
            Sb[((long)bh*128 + m_c)*1024 + n0 + ni*16 + lr] = acc[ni][r] * ISQ;
        }
}

// ---------------------------------------------------------------- softmax rows of 1024; in-place f32 -> P hi/lo u16
__global__ __launch_bounds__(256) void k_softmax(float* __restrict__ S)
{
    float* p = S + (long)blockIdx.x * 1024;
    const int t = threadIdx.x;
    float4 v = *(const float4*)(p + (t << 2));
    float m = fmaxf(fmaxf(v.x, v.y), fmaxf(v.z, v.w));
    #pragma unroll
    for (int off = 32; off > 0; off >>= 1)
        m = fmaxf(m, __shfl_xor(m, off));
    __shared__ float red[4];
    const int wave = t >> 6, lane = t & 63;
    if (lane == 0) red[wave] = m;
    __syncthreads();                      // also guarantees all row reads done
    m = fmaxf(fmaxf(red[0], red[1]), fmaxf(red[2], red[3]));
    v.x = __expf(v.x - m); v.y = __expf(v.y - m);
    v.z = __expf(v.z - m); v.w = __expf(v.w - m);
    float s = v.x + v.y + v.z + v.w;
    #pragma unroll
    for (int off = 32; off > 0; off >>= 1)
        s += __shfl_xor(s, off);
    __shared__ float red2[4];
    if (lane == 0) red2[wave] = s;
    __syncthreads();
    s = red2[0] + red2[1] + red2[2] + red2[3];
    const float inv = 1.0f / s;
    const float pv[4] = {v.x*inv, v.y*inv, v.z*inv, v.w*inv};
    u16x4 oh, ol_;
    #pragma unroll
    for (int j = 0; j < 4; ++j) {
        const u16 hi = f2bf(pv[j]);
        oh[j] = hi;
        ol_[j] = f2bf(pv[j] - bf2f(hi));
    }
    u16* q = (u16*)p;
    *(u16x4*)(q + (t << 2))        = oh;
    *(u16x4*)(q + 1024 + (t << 2)) = ol_;
}

// ---------------------------------------------------------------- PV: ao[f][m] = sum_n z[f][n]*P[m][n]
__global__ __launch_bounds__(128) void k_pvm(
    const u16* __restrict__ Zh, const u16* __restrict__ Zl,
    const u16* __restrict__ Pu, float* __restrict__ Ao, int mc)
{
    const int bh = blockIdx.z, b = bh >> 3, h = bh & 7;
    const int mt = blockIdx.x;           // 0..1
    const int f0 = blockIdx.y * 32;      // 0,32,64
    const int tid = threadIdx.x;
    const int w = tid >> 6, l = tid & 63, lr = l & 15, lg = l >> 4;
    const int fw = f0 + w*16;
    f32x4 zero = {0.f, 0.f, 0.f, 0.f};
    f32x4 acc[4] = {zero, zero, zero, zero};
    const long zbase = ((long)(b*768 + h*96 + fw + lr))*1024 + lg*8;
    const long pbase = ((long)(bh*128 + mt*64 + lr))*2048 + lg*8;
    for (int kb = 0; kb < 1024; kb += 32) {
        const bf16x8 ah = *(const bf16x8*)(Zh + zbase + kb);
        const bf16x8 al = *(const bf16x8*)(Zl + zbase + kb);
        #pragma unroll
        for (int mi = 0; mi < 4; ++mi) {
            const long pb = pbase + (long)mi*16*2048 + kb;
            const bf16x8 ph = *(const bf16x8*)(Pu + pb);
            const bf16x8 pl = *(const bf16x8*)(Pu + pb + 1024);
            acc[mi] = __builtin_amdgcn_mfma_f32_16x16x32_bf16(ah, ph, acc[mi], 0, 0, 0);
            acc[mi] = __builtin_amdgcn_mfma_f32_16x16x32_bf16(ah, pl, acc[mi], 0, 0, 0);
            acc[mi] = __builtin_amdgcn_mfma_f32_16x16x32_bf16(al, ph, acc[mi], 0, 0, 0);
        }
    }
    #pragma unroll
    for (int mi = 0; mi < 4; ++mi)
        #pragma unroll
        for (int r = 0; r < 4; ++r) {
            const int f = fw + lg*4 + r;
            const int m = mc*128 + mt*64 + mi*16 + lr;
            Ao[((long)(b*768 + h*96 + f))*1024 + m] = acc[mi][r];
        }
}

// ---------------------------------------------------------------- VN LayerNorm (+residual) [r1 verbatim]
__global__ __launch_bounds__(256) void k_vnln(
    const float* __restrict__ X, const float* __restrict__ Res,
    const float* __restrict__ g, const float* __restrict__ be,
    float* __restrict__ Out)
{
    const int b  = blockIdx.x >> 5;
    const int n  = ((blockIdx.x & 31) << 5) + threadIdx.x;
    const int ty = threadIdx.y;
    const long bbase = (long)b * (256*3*1024);
    float sum = 0.0f, sq = 0.0f;
    for (int ci = 0; ci < 32; ++ci) {
        const int c = (ty << 5) + ci;
        const long base = bbase + (long)c*3072 + n;
        const float x0 = X[base], x1 = X[base+1024], x2 = X[base+2048];
        const float nr = sqrtf(x0*x0 + x1*x1 + x2*x2) + VN_EPS;
        sum += nr; sq += nr*nr;
    }
    __shared__ float s_sum[8][32], s_sq[8][32];
    s_sum[ty][threadIdx.x] = sum; s_sq[ty][threadIdx.x] = sq;
    __syncthreads();
    __shared__ float s_mu[32], s_rs[32];
    if (ty == 0) {
        float S = 0.0f, Q = 0.0f;
        #pragma unroll
        for (int w = 0; w < 8; ++w) { S += s_sum[w][threadIdx.x]; Q += s_sq[w][threadIdx.x]; }
        const float mu = S / 256.0f;
        s_mu[threadIdx.x] = mu;
        s_rs[threadIdx.x] = rsqrtf(Q / 256.0f - mu*mu + LN_EPS);
    }
    __syncthreads();
    const float mu = s_mu[threadIdx.x], rstd = s_rs[threadIdx.x];
    for (int ci = 0; ci < 32; ++ci) {
        const int c = (ty << 5) + ci;
        const long base = bbase + (long)c*3072 + n;
        const float x0 = X[base], x1 = X[base+1024], x2 = X[base+2048];
        const float nr = sqrtf(x0*x0 + x1*x1 + x2*x2) + VN_EPS;
        const float ln = (nr - mu) * rstd * g[c] + be[c];
        const float s  = ln / nr;
        float o0 = x0*s, o1 = x1*s, o2 = x2*s;
        if (Res) { o0 += Res[base]; o1 += Res[base+1024]; o2 += Res[base+2048]; }
        Out[base] = o0; Out[base+1024] = o1; Out[base+2048] = o2;
    }
}

// ---------------------------------------------------------------- BN stats
__global__ __launch_bounds__(256) void k_bnstats(
    const float* __restrict__ X, float* __restrict__ bnst)
{
    const int c = blockIdx.x;
    const int t = threadIdx.x;
    float sum = 0.0f, sq = 0.0f;
    for (int b = 0; b < 8; ++b) {
        const long rowbase = ((long)(b*256 + c)) * 3072;
        for (int n0 = 0; n0 < 1024; n0 += 256) {
            const int n = n0 + t;
            const float x0 = X[rowbase + n], x1 = X[rowbase + 1024 + n], x2 = X[rowbase + 2048 + n];
            const float nr = sqrtf(x0*x0 + x1*x1 + x2*x2) + VN_EPS;
            sum += nr; sq += nr*nr;
        }
    }
    #pragma unroll
    for (int off = 32; off > 0; off >>= 1) {
        sum += __shfl_xor(sum, off);
        sq  += __shfl_xor(sq,  off);
    }
    __shared__ float rs[4], rq[4];
    if ((t & 63) == 0) { rs[t >> 6] = sum; rq[t >> 6] = sq; }
    __syncthreads();
    if (t == 0) {
        const float S = rs[0]+rs[1]+rs[2]+rs[3];
        const float Q = rq[0]+rq[1]+rq[2]+rq[3];
        const float mu = S / 8192.0f;
        bnst[c] = mu;
        bnst[256 + c] = rsqrtf(Q / 8192.0f - mu*mu + BN_EPS);
    }
}

// ---------------------------------------------------------------- BN apply in place
__global__ __launch_bounds__(256) void k_bnapply(
    float* __restrict__ X, const float* __restrict__ bnst,
    const float* __restrict__ g, const float* __restrict__ be)
{
    const long i = (long)blockIdx.x * 256 + threadIdx.x;
    const int  n  = (int)(i & 1023);
    const long bc = i >> 10;
    const int  c  = (int)(bc & 255);
    const long base = bc * 3072 + n;
    const float x0 = X[base], x1 = X[base+1024], x2 = X[base+2048];
    const float nr = sqrtf(x0*x0 + x1*x1 + x2*x2) + VN_EPS;
    const float bn = (nr - bnst[c]) * bnst[256 + c] * g[c] + be[c];
    const float s  = bn / nr;
    X[base]      = x0*s;
    X[base+1024] = x1*s;
    X[base+2048] = x2*s;
}

// ---------------------------------------------------------------- VN leaky relu (slope 0) in place
__global__ __launch_bounds__(256) void k_leaky(
    float* __restrict__ X, const float* __restrict__ Dd)
{
    const long i = (long)blockIdx.x * 256 + threadIdx.x;
    const long base = (i >> 10) * 3072 + (i & 1023);
    const float x0 = X[base], x1 = X[base+1024], x2 = X[base+2048];
    const float d0 = Dd[base], d1 = Dd[base+1024], d2 = Dd[base+2048];
    const float dot = x0*d0 + x1*d1 + x2*d2;
    if (dot < 0.0f) {
        const float f = dot / (d0*d0 + d1*d1 + d2*d2 + VN_EPS);
        X[base]      = x0 - f*d0;
        X[base+1024] = x1 - f*d1;
        X[base+2048] = x2 - f*d2;
    }
}

// ================================================================ launch
extern "C" void kernel_launch(void* const* d_in, const int* in_sizes, int n_in,
                              void* d_out, int out_size, void* d_ws, size_t ws_size,
                              hipStream_t stream)
{
    const float* x    = (const float*)d_in[0];
    const float* Wq   = (const float*)d_in[1];
    const float* bq   = (const float*)d_in[2];
    const float* Wk   = (const float*)d_in[3];
    const float* bk   = (const float*)d_in[4];
    const float* Wz   = (const float*)d_in[5];
    const float* bz   = (const float*)d_in[6];
    const float* Wo   = (const float*)d_in[7];
    const float* bo   = (const float*)d_in[8];
    const float* ln1g = (const float*)d_in[9];
    const float* ln1b = (const float*)d_in[10];
    const float* Wm1  = (const float*)d_in[11];
    const float* bm1  = (const float*)d_in[12];
    const float* bng  = (const float*)d_in[13];
    const float* bnb  = (const float*)d_in[14];
    const float* Wr   = (const float*)d_in[15];
    const float* Wm2  = (const float*)d_in[16];
    const float* bm2  = (const float*)d_in[17];
    const float* ln2g = (const float*)d_in[18];
    const float* ln2b = (const float*)d_in[19];
    float* out = (float*)d_out;

    char* wsb = (char*)d_ws;
    u16*   qh  = (u16*)(wsb + 0);              // [bh][1024][96] hi
    u16*   ql  = (u16*)(wsb + 12582912);
    u16*   kh  = (u16*)(wsb + 25165824);
    u16*   kl  = (u16*)(wsb + 37748736);
    u16*   zh  = (u16*)(wsb + 50331648);       // [b][c][d][n] hi
    u16*   zl  = (u16*)(wsb + 62914560);
    float* Sb  = (float*)(wsb + 75497472);     // [64][128][1024] f32 == [64][128][2048] u16
    u16*   Pu  = (u16*)(wsb + 75497472);
    u16*   wth = (u16*)(wsb + 109051904);      // 7*65536
    u16*   wtl = (u16*)(wsb + 109969408);
    float* uall= (float*)(wsb + 110886912);    // 6*768
    float* bnst= (float*)(wsb + 110905344);    // 512
    // phase C aliases (attention buffers dead)
    float* ao  = out;                          // d_out as attn-out scratch (r1-proven)
    float* y0f = (float*)(wsb + 0);
    float* y   = (float*)(wsb + 25165824);
    float* h   = (float*)(wsb + 50331648);
    float* dv  = (float*)(wsb + 75497472);
    float* h2  = (float*)(wsb + 0);

    const dim3 GC(16, 4, 24);

    k_u<<<6, 256, 0, stream>>>(bq, bk, bz, bo, bm1, bm2, uall);
    k_wtrans<<<dim3(4,4,7), 256, 0, stream>>>(Wq, Wk, Wz, Wo, Wm1, Wr, Wm2, wth, wtl);

    // projections
    k_cgemm<2><<<GC, 256, 0, stream>>>(x, wth + 0*65536, wtl + 0*65536, uall + 0*768, nullptr, qh, ql);
    k_cgemm<2><<<GC, 256, 0, stream>>>(x, wth + 1*65536, wtl + 1*65536, uall + 1*768, nullptr, kh, kl);
    k_cgemm<1><<<GC, 256, 0, stream>>>(x, wth + 2*65536, wtl + 2*65536, uall + 2*768, nullptr, zh, zl);

    // attention, 8 chunks of 128 m-rows
    for (int mc = 0; mc < 8; ++mc) {
        k_scores<<<dim3(16,2,64), 256, 0, stream>>>(qh, ql, kh, kl, Sb, mc);
        k_softmax<<<8192, 256, 0, stream>>>(Sb);
        k_pvm<<<dim3(2,3,64), 128, 0, stream>>>(zh, zl, Pu, ao, mc);
    }

    // out projection + LN1 (+ residual x)
    k_cgemm<0><<<GC, 256, 0, stream>>>(ao, wth + 3*65536, wtl + 3*65536, uall + 3*768, y0f, nullptr, nullptr);
    k_vnln<<<256, dim3(32,8), 0, stream>>>(y0f, x, ln1g, ln1b, y);

    // MLP
    k_cgemm<0><<<GC, 256, 0, stream>>>(y, wth + 4*65536, wtl + 4*65536, uall + 4*768, h, nullptr, nullptr);
    k_bnstats<<<256, 256, 0, stream>>>(h, bnst);
    k_bnapply<<<8192, 256, 0, stream>>>(h, bnst, bng, bnb);
    k_cgemm<0><<<GC, 256, 0, stream>>>(h, wth + 5*65536, wtl + 5*65536, (const float*)nullptr, dv, nullptr, nullptr);
    k_leaky<<<8192, 256, 0, stream>>>(h, dv);
    k_cgemm<0><<<GC, 256, 0, stream>>>(h, wth + 6*65536, wtl + 6*65536, uall + 5*768, h2, nullptr, nullptr);
    k_vnln<<<256, dim3(32,8), 0, stream>>>(h2, y, ln2g, ln2b, out);
}

// Round 8
// 591.078 us; speedup vs baseline: 1.9818x; 1.5614x over previous
//
#include <hip/hip_runtime.h>
#include <math.h>

typedef __attribute__((ext_vector_type(8))) short bf16x8;
typedef __attribute__((ext_vector_type(4))) float f32x4;
typedef unsigned short u16;
typedef __attribute__((ext_vector_type(4))) unsigned short u16x4;
typedef __attribute__((ext_vector_type(8))) unsigned short u16x8;

#define VN_EPS 1e-6f
#define LN_EPS 1e-5f
#define BN_EPS 1e-5f
#define ISQ 0.10206207261596575f

__device__ __forceinline__ u16 f2bf(float f) {
    unsigned u = __builtin_bit_cast(unsigned, f);
    return (u16)((u + 0x7FFFu + ((u >> 16) & 1u)) >> 16);
}
__device__ __forceinline__ float bf2f(u16 h) {
    unsigned u = ((unsigned)h) << 16;
    return __builtin_bit_cast(float, u);
}

// ---------------------------------------------------------------- u = eps*b/||b||
__global__ __launch_bounds__(256) void k_u(
    const float* __restrict__ b0, const float* __restrict__ b1,
    const float* __restrict__ b2, const float* __restrict__ b3,
    const float* __restrict__ b4, const float* __restrict__ b5,
    float* __restrict__ uall)
{
    const float* bs[6] = {b0, b1, b2, b3, b4, b5};
    const float* bp = bs[blockIdx.x];
    const int co = threadIdx.x;
    const float v0 = bp[co*3+0], v1 = bp[co*3+1], v2 = bp[co*3+2];
    const float inv = rsqrtf(v0*v0 + v1*v1 + v2*v2);
    float* u = uall + blockIdx.x*768 + co*3;
    u[0] = VN_EPS*v0*inv; u[1] = VN_EPS*v1*inv; u[2] = VN_EPS*v2*inv;
}

// ---------------------------------------------------------------- W f32 [i][o] -> Wt hi/lo bf16 [o][i]
__global__ __launch_bounds__(256) void k_wtrans(
    const float* __restrict__ w0, const float* __restrict__ w1,
    const float* __restrict__ w2, const float* __restrict__ w3,
    const float* __restrict__ w4, const float* __restrict__ w5,
    const float* __restrict__ w6, u16* __restrict__ wth, u16* __restrict__ wtl)
{
    const int wi = blockIdx.z;
    const float* W = (wi==0)?w0:(wi==1)?w1:(wi==2)?w2:(wi==3)?w3:(wi==4)?w4:(wi==5)?w5:w6;
    u16* WtH = wth + (long)wi*65536;
    u16* WtL = wtl + (long)wi*65536;
    const int i0 = blockIdx.y*64, o0 = blockIdx.x*64;
    __shared__ float st[64][67];
    const int t = threadIdx.x, q = t >> 6, lane = t & 63;
    for (int j = 0; j < 16; ++j) {
        const int i = q*16 + j;
        st[i][lane] = W[(i0 + i)*256 + o0 + lane];
    }
    __syncthreads();
    for (int j = 0; j < 16; ++j) {
        const int o = q*16 + j;
        const float v = st[lane][o];
        const u16 hi = f2bf(v);
        WtH[(o0 + o)*256 + i0 + lane] = hi;
        WtL[(o0 + o)*256 + i0 + lane] = f2bf(v - bf2f(hi));
    }
}

// ---------------------------------------------------------------- split-bf16 channel GEMM [r7 verbatim]
template<int MODE>
__global__ __launch_bounds__(256) void k_cgemm(
    const float* __restrict__ X, const u16* __restrict__ WtH, const u16* __restrict__ WtL,
    const float* __restrict__ U,
    float* __restrict__ OutF, u16* __restrict__ OutH, u16* __restrict__ OutL)
{
    __shared__ u16 sh[32768];
    const int tid = threadIdx.x;
    const int b = blockIdx.z / 3, d = blockIdx.z % 3;
    const int n0 = blockIdx.x * 64;
    const int co0 = blockIdx.y * 64;

    {
        const int tn = (tid & 15) * 4;
        const int ti = (tid >> 4) * 4;
        #pragma unroll
        for (int it = 0; it < 4; ++it) {
            const int i_l = it*64 + ti;
            const long rb = (((long)(b*256 + i_l))*3 + d)*1024 + n0 + tn;
            const float4 r0 = *(const float4*)&X[rb];
            const float4 r1 = *(const float4*)&X[rb + 3072];
            const float4 r2 = *(const float4*)&X[rb + 6144];
            const float4 r3 = *(const float4*)&X[rb + 9216];
            const float vals[4][4] = {
                {r0.x, r1.x, r2.x, r3.x},
                {r0.y, r1.y, r2.y, r3.y},
                {r0.z, r1.z, r2.z, r3.z},
                {r0.w, r1.w, r2.w, r3.w}};
            #pragma unroll
            for (int j = 0; j < 4; ++j) {
                const int n = tn + j;
                u16x4 hv, lv;
                #pragma unroll
                for (int e = 0; e < 4; ++e) {
                    const float v = vals[j][e];
                    const u16 hi = f2bf(v);
                    hv[e] = hi;
                    lv[e] = f2bf(v - bf2f(hi));
                }
                const int slot = i_l >> 3;
                const int idx = n*256 + ((((slot ^ (n & 7)) << 3)) | (i_l & 4));
                *(u16x4*)&sh[idx] = hv;
                *(u16x4*)&sh[16384 + idx] = lv;
            }
        }
    }
    __syncthreads();

    const int w = tid >> 6, l = tid & 63;
    const int lr = l & 15, lg = l >> 4;

    f32x4 zero = {0.f, 0.f, 0.f, 0.f};
    f32x4 acc[4] = {zero, zero, zero, zero};

    const long arow = (long)(co0 + w*16 + lr)*256 + lg*8;
    #pragma unroll
    for (int s = 0; s < 8; ++s) {
        const bf16x8 ah = *(const bf16x8*)(WtH + arow + s*32);
        const bf16x8 al = *(const bf16x8*)(WtL + arow + s*32);
        #pragma unroll
        for (int ni = 0; ni < 4; ++ni) {
            const int row = ni*16 + lr;
            const int slot = s*4 + lg;
            const int idx = row*256 + ((slot ^ (row & 7)) << 3);
            const bf16x8 bh_ = *(const bf16x8*)&sh[idx];
            const bf16x8 bl_ = *(const bf16x8*)&sh[16384 + idx];
            acc[ni] = __builtin_amdgcn_mfma_f32_16x16x32_bf16(ah, bh_, acc[ni], 0, 0, 0);
            acc[ni] = __builtin_amdgcn_mfma_f32_16x16x32_bf16(ah, bl_, acc[ni], 0, 0, 0);
            acc[ni] = __builtin_amdgcn_mfma_f32_16x16x32_bf16(al, bh_, acc[ni], 0, 0, 0);
        }
    }

    if constexpr (MODE == 0) {
        #pragma unroll
        for (int ni = 0; ni < 4; ++ni)
            #pragma unroll
            for (int r = 0; r < 4; ++r) {
                const int co = co0 + w*16 + lg*4 + r;
                const int nn = n0 + ni*16 + lr;
                float v = acc[ni][r];
                if (U) v += U[co*3 + d];
                OutF[(((long)(b*256 + co))*3 + d)*1024 + nn] = v;
            }
    } else if constexpr (MODE == 1) {
        #pragma unroll
        for (int ni = 0; ni < 4; ++ni)
            #pragma unroll
            for (int r = 0; r < 4; ++r) {
                const int co = co0 + w*16 + lg*4 + r;
                const int nn = n0 + ni*16 + lr;
                float v = acc[ni][r] + U[co*3 + d];
                const long idx = (((long)(b*256 + co))*3 + d)*1024 + nn;
                const u16 hi = f2bf(v);
                OutH[idx] = hi;
                OutL[idx] = f2bf(v - bf2f(hi));
            }
    } else {
        __syncthreads();
        u16* olh = sh;
        u16* oll = sh + 8448;
        #pragma unroll
        for (int ni = 0; ni < 4; ++ni)
            #pragma unroll
            for (int r = 0; r < 4; ++r) {
                const int co_l = w*16 + lg*4 + r;
                float v = acc[ni][r] + U[(co0 + co_l)*3 + d];
                const u16 hi = f2bf(v);
                olh[co_l*66 + ni*16 + lr] = hi;
                oll[co_l*66 + ni*16 + lr] = f2bf(v - bf2f(hi));
            }
        __syncthreads();
        const int n_l = tid & 63, grp = tid >> 6;
        const int h = (co0 >> 5) + (grp >> 1);
        const long base = ((long)(b*8 + h)*1024 + n0 + n_l)*96 + d*32 + (grp & 1)*16;
        u16x8 v0h, v1h, v0l, v1l;
        #pragma unroll
        for (int p = 0; p < 8; ++p) {
            v0h[p] = olh[(grp*16 + p)*66 + n_l];
            v1h[p] = olh[(grp*16 + 8 + p)*66 + n_l];
            v0l[p] = oll[(grp*16 + p)*66 + n_l];
            v1l[p] = oll[(grp*16 + 8 + p)*66 + n_l];
        }
        *(u16x8*)&OutH[base]     = v0h;
        *(u16x8*)&OutH[base + 8] = v1h;
        *(u16x8*)&OutL[base]     = v0l;
        *(u16x8*)&OutL[base + 8] = v1l;
    }
}

// ---------------------------------------------------------------- fused attention per (bh, 16 m-rows)
// q/k: [bh][n][96] hi/lo (head-major). z: [b][c][d][n] hi/lo. Ao: [b*768 + h*96 + f][m] f32.
__global__ __launch_bounds__(256) void k_attn(
    const u16* __restrict__ Qh, const u16* __restrict__ Ql,
    const u16* __restrict__ Kh, const u16* __restrict__ Kl,
    const u16* __restrict__ Zh, const u16* __restrict__ Zl,
    float* __restrict__ Ao)
{
    const int mt = blockIdx.x, h = blockIdx.y, b = blockIdx.z;
    const int bh = b*8 + h;
    const int m0 = mt*16;
    const int tid = threadIdx.x;
    const int w = tid >> 6, l = tid & 63, lr = l & 15, lg = l >> 4;

    __shared__ float S[16*1024];       // 64 KB; becomes P hi/lo (row-local) after softmax
    __shared__ float outl[16*100];
    __shared__ float inv16[16];

    f32x4 zero = {0.f, 0.f, 0.f, 0.f};

    // ---- phase 1: S[m][n] = ISQ * sum_f q[m][f]*k[n][f]   (split-bf16, 3 MFMA per pair)
    const long qbase = ((long)bh*1024 + m0 + lr)*96 + lg*8;
    bf16x8 qhf[3], qlf[3];
    #pragma unroll
    for (int s = 0; s < 3; ++s) {
        qhf[s] = *(const bf16x8*)(Qh + qbase + s*32);
        qlf[s] = *(const bf16x8*)(Ql + qbase + s*32);
    }
    for (int nf = 0; nf < 16; ++nf) {
        const int n0 = w*256 + nf*16;
        const long kb = ((long)bh*1024 + n0 + lr)*96 + lg*8;
        f32x4 acc = zero;
        #pragma unroll
        for (int s = 0; s < 3; ++s) {
            const bf16x8 khf = *(const bf16x8*)(Kh + kb + s*32);
            const bf16x8 klf = *(const bf16x8*)(Kl + kb + s*32);
            acc = __builtin_amdgcn_mfma_f32_16x16x32_bf16(qhf[s], khf, acc, 0, 0, 0);
            acc = __builtin_amdgcn_mfma_f32_16x16x32_bf16(qhf[s], klf, acc, 0, 0, 0);
            acc = __builtin_amdgcn_mfma_f32_16x16x32_bf16(qlf[s], khf, acc, 0, 0, 0);
        }
        #pragma unroll
        for (int r = 0; r < 4; ++r)
            S[(lg*4 + r)*1024 + n0 + lr] = acc[r] * ISQ;
    }
    __syncthreads();

    // ---- phase 2: softmax (row in registers; unnormalized P hi/lo back into S, row-local, swizzled)
    {
        const int r = tid >> 4, s = tid & 15;
        float preg[64];
        float mx = -1e30f;
        #pragma unroll
        for (int j = 0; j < 64; ++j) {
            preg[j] = S[r*1024 + j*16 + s];
            mx = fmaxf(mx, preg[j]);
        }
        #pragma unroll
        for (int off = 1; off < 16; off <<= 1)
            mx = fmaxf(mx, __shfl_xor(mx, off));
        float sm = 0.f;
        #pragma unroll
        for (int j = 0; j < 64; ++j) {
            const float p = __expf(preg[j] - mx);
            preg[j] = p;
            sm += p;
        }
        #pragma unroll
        for (int off = 1; off < 16; off <<= 1)
            sm += __shfl_xor(sm, off);
        if (s == 0) inv16[r] = 1.0f / sm;
        __syncthreads();
        char* Sb = (char*)S;
        #pragma unroll
        for (int j = 0; j < 64; ++j) {
            const int n = j*16 + s;
            const u16 hi = f2bf(preg[j]);
            const u16 lo = f2bf(preg[j] - bf2f(hi));
            const int byoff = (n*2) ^ ((r & 7) << 4);   // swizzle within 2KB half-row
            *(u16*)(Sb + r*4096 + byoff)        = hi;
            *(u16*)(Sb + r*4096 + 2048 + byoff) = lo;
        }
    }
    __syncthreads();

    // ---- phase 3: PV partials over this wave's 256-col n-range
    f32x4 acc2[6];
    #pragma unroll
    for (int f = 0; f < 6; ++f) acc2[f] = zero;
    const long zrow = (long)(b*768 + h*96);
    const char* Sb = (const char*)S;
    for (int kb = 0; kb < 8; ++kb) {
        const int n = w*256 + kb*32 + lg*8;
        const int byoff = lr*4096 + (((n*2)) ^ ((lr & 7) << 4));
        const bf16x8 ph = *(const bf16x8*)(Sb + byoff);
        const bf16x8 pl = *(const bf16x8*)(Sb + byoff + 2048);
        #pragma unroll
        for (int ff = 0; ff < 6; ++ff) {
            const long zb = (zrow + ff*16 + lr)*1024 + n;
            const bf16x8 azh = *(const bf16x8*)(Zh + zb);
            const bf16x8 azl = *(const bf16x8*)(Zl + zb);
            acc2[ff] = __builtin_amdgcn_mfma_f32_16x16x32_bf16(ph, azh, acc2[ff], 0, 0, 0);
            acc2[ff] = __builtin_amdgcn_mfma_f32_16x16x32_bf16(ph, azl, acc2[ff], 0, 0, 0);
            acc2[ff] = __builtin_amdgcn_mfma_f32_16x16x32_bf16(pl, azh, acc2[ff], 0, 0, 0);
        }
    }
    __syncthreads();
    // staged deterministic cross-wave reduce
    for (int wv = 0; wv < 4; ++wv) {
        if (w == wv) {
            #pragma unroll
            for (int ff = 0; ff < 6; ++ff)
                #pragma unroll
                for (int r = 0; r < 4; ++r) {
                    const int m = lg*4 + r, f = ff*16 + lr;
                    if (wv == 0) outl[m*100 + f] = acc2[ff][r];
                    else         outl[m*100 + f] += acc2[ff][r];
                }
        }
        __syncthreads();
    }
    // ---- phase 4: normalized, coalesced write
    for (int idx = tid; idx < 384; idx += 256) {
        const int f = idx >> 2, mg = idx & 3;
        float4 o;
        o.x = outl[(mg*4+0)*100 + f] * inv16[mg*4+0];
        o.y = outl[(mg*4+1)*100 + f] * inv16[mg*4+1];
        o.z = outl[(mg*4+2)*100 + f] * inv16[mg*4+2];
        o.w = outl[(mg*4+3)*100 + f] * inv16[mg*4+3];
        *(float4*)&Ao[(long)(b*768 + h*96 + f)*1024 + m0 + mg*4] = o;
    }
}

// ---------------------------------------------------------------- VN LayerNorm (+residual) [r1 verbatim]
__global__ __launch_bounds__(256) void k_vnln(
    const float* __restrict__ X, const float* __restrict__ Res,
    const float* __restrict__ g, const float* __restrict__ be,
    float* __restrict__ Out)
{
    const int b  = blockIdx.x >> 5;
    const int n  = ((blockIdx.x & 31) << 5) + threadIdx.x;
    const int ty = threadIdx.y;
    const long bbase = (long)b * (256*3*1024);
    float sum = 0.0f, sq = 0.0f;
    for (int ci = 0; ci < 32; ++ci) {
        const int c = (ty << 5) + ci;
        const long base = bbase + (long)c*3072 + n;
        const float x0 = X[base], x1 = X[base+1024], x2 = X[base+2048];
        const float nr = sqrtf(x0*x0 + x1*x1 + x2*x2) + VN_EPS;
        sum += nr; sq += nr*nr;
    }
    __shared__ float s_sum[8][32], s_sq[8][32];
    s_sum[ty][threadIdx.x] = sum; s_sq[ty][threadIdx.x] = sq;
    __syncthreads();
    __shared__ float s_mu[32], s_rs[32];
    if (ty == 0) {
        float S = 0.0f, Q = 0.0f;
        #pragma unroll
        for (int w = 0; w < 8; ++w) { S += s_sum[w][threadIdx.x]; Q += s_sq[w][threadIdx.x]; }
        const float mu = S / 256.0f;
        s_mu[threadIdx.x] = mu;
        s_rs[threadIdx.x] = rsqrtf(Q / 256.0f - mu*mu + LN_EPS);
    }
    __syncthreads();
    const float mu = s_mu[threadIdx.x], rstd = s_rs[threadIdx.x];
    for (int ci = 0; ci < 32; ++ci) {
        const int c = (ty << 5) + ci;
        const long base = bbase + (long)c*3072 + n;
        const float x0 = X[base], x1 = X[base+1024], x2 = X[base+2048];
        const float nr = sqrtf(x0*x0 + x1*x1 + x2*x2) + VN_EPS;
        const float ln = (nr - mu) * rstd * g[c] + be[c];
        const float s  = ln / nr;
        float o0 = x0*s, o1 = x1*s, o2 = x2*s;
        if (Res) { o0 += Res[base]; o1 += Res[base+1024]; o2 += Res[base+2048]; }
        Out[base] = o0; Out[base+1024] = o1; Out[base+2048] = o2;
    }
}

// ---------------------------------------------------------------- BN stats [r7 verbatim]
__global__ __launch_bounds__(256) void k_bnstats(
    const float* __restrict__ X, float* __restrict__ bnst)
{
    const int c = blockIdx.x;
    const int t = threadIdx.x;
    float sum = 0.0f, sq = 0.0f;
    for (int b = 0; b < 8; ++b) {
        const long rowbase = ((long)(b*256 + c)) * 3072;
        for (int n0 = 0; n0 < 1024; n0 += 256) {
            const int n = n0 + t;
            const float x0 = X[rowbase + n], x1 = X[rowbase + 1024 + n], x2 = X[rowbase + 2048 + n];
            const float nr = sqrtf(x0*x0 + x1*x1 + x2*x2) + VN_EPS;
            sum += nr; sq += nr*nr;
        }
    }
    #pragma unroll
    for (int off = 32; off > 0; off >>= 1) {
        sum += __shfl_xor(sum, off);
        sq  += __shfl_xor(sq,  off);
    }
    __shared__ float rs[4], rq[4];
    if ((t & 63) == 0) { rs[t >> 6] = sum; rq[t >> 6] = sq; }
    __syncthreads();
    if (t == 0) {
        const float S = rs[0]+rs[1]+rs[2]+rs[3];
        const float Q = rq[0]+rq[1]+rq[2]+rq[3];
        const float mu = S / 8192.0f;
        bnst[c] = mu;
        bnst[256 + c] = rsqrtf(Q / 8192.0f - mu*mu + BN_EPS);
    }
}

// ---------------------------------------------------------------- BN apply in place [r7 verbatim]
__global__ __launch_bounds__(256) void k_bnapply(
    float* __restrict__ X, const float* __restrict__ bnst,
    const float* __restrict__ g, const float* __restrict__ be)
{
    const long i = (long)blockIdx.x * 256 + threadIdx.x;
    const int  n  = (int)(i & 1023);
    const long bc = i >> 10;
    const int  c  = (int)(bc & 255);
    const long base = bc * 3072 + n;
    const float x0 = X[base], x1 = X[base+1024], x2 = X[base+2048];
    const float nr = sqrtf(x0*x0 + x1*x1 + x2*x2) + VN_EPS;
    const float bn = (nr - bnst[c]) * bnst[256 + c] * g[c] + be[c];
    const float s  = bn / nr;
    X[base]      = x0*s;
    X[base+1024] = x1*s;
    X[base+2048] = x2*s;
}

// ---------------------------------------------------------------- VN leaky relu (slope 0) in place [r7 verbatim]
__global__ __launch_bounds__(256) void k_leaky(
    float* __restrict__ X, const float* __restrict__ Dd)
{
    const long i = (long)blockIdx.x * 256 + threadIdx.x;
    const long base = (i >> 10) * 3072 + (i & 1023);
    const float x0 = X[base], x1 = X[base+1024], x2 = X[base+2048];
    const float d0 = Dd[base], d1 = Dd[base+1024], d2 = Dd[base+2048];
    const float dot = x0*d0 + x1*d1 + x2*d2;
    if (dot < 0.0f) {
        const float f = dot / (d0*d0 + d1*d1 + d2*d2 + VN_EPS);
        X[base]      = x0 - f*d0;
        X[base+1024] = x1 - f*d1;
        X[base+2048] = x2 - f*d2;
    }
}

// ================================================================ launch
extern "C" void kernel_launch(void* const* d_in, const int* in_sizes, int n_in,
                              void* d_out, int out_size, void* d_ws, size_t ws_size,
                              hipStream_t stream)
{
    const float* x    = (const float*)d_in[0];
    const float* Wq   = (const float*)d_in[1];
    const float* bq   = (const float*)d_in[2];
    const float* Wk   = (const float*)d_in[3];
    const float* bk   = (const float*)d_in[4];
    const float* Wz   = (const float*)d_in[5];
    const float* bz   = (const float*)d_in[6];
    const float* Wo   = (const float*)d_in[7];
    const float* bo   = (const float*)d_in[8];
    const float* ln1g = (const float*)d_in[9];
    const float* ln1b = (const float*)d_in[10];
    const float* Wm1  = (const float*)d_in[11];
    const float* bm1  = (const float*)d_in[12];
    const float* bng  = (const float*)d_in[13];
    const float* bnb  = (const float*)d_in[14];
    const float* Wr   = (const float*)d_in[15];
    const float* Wm2  = (const float*)d_in[16];
    const float* bm2  = (const float*)d_in[17];
    const float* ln2g = (const float*)d_in[18];
    const float* ln2b = (const float*)d_in[19];
    float* out = (float*)d_out;

    char* wsb = (char*)d_ws;
    u16*   qh  = (u16*)(wsb + 0);
    u16*   ql  = (u16*)(wsb + 12582912);
    u16*   kh  = (u16*)(wsb + 25165824);
    u16*   kl  = (u16*)(wsb + 37748736);
    u16*   zh  = (u16*)(wsb + 50331648);
    u16*   zl  = (u16*)(wsb + 62914560);
    u16*   wth = (u16*)(wsb + 109051904);
    u16*   wtl = (u16*)(wsb + 109969408);
    float* uall= (float*)(wsb + 110886912);
    float* bnst= (float*)(wsb + 110905344);
    // phase C aliases (attention buffers dead)
    float* ao  = out;                          // d_out as attn-out scratch
    float* y0f = (float*)(wsb + 0);
    float* y   = (float*)(wsb + 25165824);
    float* h   = (float*)(wsb + 50331648);
    float* dv  = (float*)(wsb + 75497472);
    float* h2  = (float*)(wsb + 0);

    const dim3 GC(16, 4, 24);

    k_u<<<6, 256, 0, stream>>>(bq, bk, bz, bo, bm1, bm2, uall);
    k_wtrans<<<dim3(4,4,7), 256, 0, stream>>>(Wq, Wk, Wz, Wo, Wm1, Wr, Wm2, wth, wtl);

    // projections
    k_cgemm<2><<<GC, 256, 0, stream>>>(x, wth + 0*65536, wtl + 0*65536, uall + 0*768, nullptr, qh, ql);
    k_cgemm<2><<<GC, 256, 0, stream>>>(x, wth + 1*65536, wtl + 1*65536, uall + 1*768, nullptr, kh, kl);
    k_cgemm<1><<<GC, 256, 0, stream>>>(x, wth + 2*65536, wtl + 2*65536, uall + 2*768, nullptr, zh, zl);

    // fused attention
    k_attn<<<dim3(64, 8, 8), 256, 0, stream>>>(qh, ql, kh, kl, zh, zl, ao);

    // out projection + LN1 (+ residual x)
    k_cgemm<0><<<GC, 256, 0, stream>>>(ao, wth + 3*65536, wtl + 3*65536, uall + 3*768, y0f, nullptr, nullptr);
    k_vnln<<<256, dim3(32,8), 0, stream>>>(y0f, x, ln1g, ln1b, y);

    // MLP
    k_cgemm<0><<<GC, 256, 0, stream>>>(y, wth + 4*65536, wtl + 4*65536, uall + 4*768, h, nullptr, nullptr);
    k_bnstats<<<256, 256, 0, stream>>>(h, bnst);
    k_bnapply<<<8192, 256, 0, stream>>>(h, bnst, bng, bnb);
    k_cgemm<0><<<GC, 256, 0, stream>>>(h, wth + 5*65536, wtl + 5*65536, (const float*)nullptr, dv, nullptr, nullptr);
    k_leaky<<<8192, 256, 0, stream>>>(h, dv);
    k_cgemm<0><<<GC, 256, 0, stream>>>(h, wth + 6*65536, wtl + 6*65536, uall + 5*768, h2, nullptr, nullptr);
    k_vnln<<<256, dim3(32,8), 0, stream>>>(h2, y, ln2g, ln2b, out);
}

// Round 9
// 576.252 us; speedup vs baseline: 2.0328x; 1.0257x over previous
//
#include <hip/hip_runtime.h>
#include <math.h>

typedef __attribute__((ext_vector_type(8))) short bf16x8;
typedef __attribute__((ext_vector_type(4))) float f32x4;
typedef unsigned short u16;
typedef __attribute__((ext_vector_type(4))) unsigned short u16x4;
typedef __attribute__((ext_vector_type(8))) unsigned short u16x8;

#define VN_EPS 1e-6f
#define LN_EPS 1e-5f
#define BN_EPS 1e-5f
#define ISQ 0.10206207261596575f

__device__ __forceinline__ u16 f2bf(float f) {
    unsigned u = __builtin_bit_cast(unsigned, f);
    return (u16)((u + 0x7FFFu + ((u >> 16) & 1u)) >> 16);
}
__device__ __forceinline__ float bf2f(u16 h) {
    unsigned u = ((unsigned)h) << 16;
    return __builtin_bit_cast(float, u);
}

// ---------------------------------------------------------------- u = eps*b/||b||
__global__ __launch_bounds__(256) void k_u(
    const float* __restrict__ b0, const float* __restrict__ b1,
    const float* __restrict__ b2, const float* __restrict__ b3,
    const float* __restrict__ b4, const float* __restrict__ b5,
    float* __restrict__ uall)
{
    const float* bs[6] = {b0, b1, b2, b3, b4, b5};
    const float* bp = bs[blockIdx.x];
    const int co = threadIdx.x;
    const float v0 = bp[co*3+0], v1 = bp[co*3+1], v2 = bp[co*3+2];
    const float inv = rsqrtf(v0*v0 + v1*v1 + v2*v2);
    float* u = uall + blockIdx.x*768 + co*3;
    u[0] = VN_EPS*v0*inv; u[1] = VN_EPS*v1*inv; u[2] = VN_EPS*v2*inv;
}

// ---------------------------------------------------------------- W f32 [i][o] -> Wt hi/lo bf16 [o][i]
__global__ __launch_bounds__(256) void k_wtrans(
    const float* __restrict__ w0, const float* __restrict__ w1,
    const float* __restrict__ w2, const float* __restrict__ w3,
    const float* __restrict__ w4, const float* __restrict__ w5,
    const float* __restrict__ w6, u16* __restrict__ wth, u16* __restrict__ wtl)
{
    const int wi = blockIdx.z;
    const float* W = (wi==0)?w0:(wi==1)?w1:(wi==2)?w2:(wi==3)?w3:(wi==4)?w4:(wi==5)?w5:w6;
    u16* WtH = wth + (long)wi*65536;
    u16* WtL = wtl + (long)wi*65536;
    const int i0 = blockIdx.y*64, o0 = blockIdx.x*64;
    __shared__ float st[64][67];
    const int t = threadIdx.x, q = t >> 6, lane = t & 63;
    for (int j = 0; j < 16; ++j) {
        const int i = q*16 + j;
        st[i][lane] = W[(i0 + i)*256 + o0 + lane];
    }
    __syncthreads();
    for (int j = 0; j < 16; ++j) {
        const int o = q*16 + j;
        const float v = st[lane][o];
        const u16 hi = f2bf(v);
        WtH[(o0 + o)*256 + i0 + lane] = hi;
        WtL[(o0 + o)*256 + i0 + lane] = f2bf(v - bf2f(hi));
    }
}

// ---------------------------------------------------------------- split-bf16 channel GEMM [r7 verbatim]
template<int MODE>
__global__ __launch_bounds__(256) void k_cgemm(
    const float* __restrict__ X, const u16* __restrict__ WtH, const u16* __restrict__ WtL,
    const float* __restrict__ U,
    float* __restrict__ OutF, u16* __restrict__ OutH, u16* __restrict__ OutL)
{
    __shared__ u16 sh[32768];
    const int tid = threadIdx.x;
    const int b = blockIdx.z / 3, d = blockIdx.z % 3;
    const int n0 = blockIdx.x * 64;
    const int co0 = blockIdx.y * 64;

    {
        const int tn = (tid & 15) * 4;
        const int ti = (tid >> 4) * 4;
        #pragma unroll
        for (int it = 0; it < 4; ++it) {
            const int i_l = it*64 + ti;
            const long rb = (((long)(b*256 + i_l))*3 + d)*1024 + n0 + tn;
            const float4 r0 = *(const float4*)&X[rb];
            const float4 r1 = *(const float4*)&X[rb + 3072];
            const float4 r2 = *(const float4*)&X[rb + 6144];
            const float4 r3 = *(const float4*)&X[rb + 9216];
            const float vals[4][4] = {
                {r0.x, r1.x, r2.x, r3.x},
                {r0.y, r1.y, r2.y, r3.y},
                {r0.z, r1.z, r2.z, r3.z},
                {r0.w, r1.w, r2.w, r3.w}};
            #pragma unroll
            for (int j = 0; j < 4; ++j) {
                const int n = tn + j;
                u16x4 hv, lv;
                #pragma unroll
                for (int e = 0; e < 4; ++e) {
                    const float v = vals[j][e];
                    const u16 hi = f2bf(v);
                    hv[e] = hi;
                    lv[e] = f2bf(v - bf2f(hi));
                }
                const int slot = i_l >> 3;
                const int idx = n*256 + ((((slot ^ (n & 7)) << 3)) | (i_l & 4));
                *(u16x4*)&sh[idx] = hv;
                *(u16x4*)&sh[16384 + idx] = lv;
            }
        }
    }
    __syncthreads();

    const int w = tid >> 6, l = tid & 63;
    const int lr = l & 15, lg = l >> 4;

    f32x4 zero = {0.f, 0.f, 0.f, 0.f};
    f32x4 acc[4] = {zero, zero, zero, zero};

    const long arow = (long)(co0 + w*16 + lr)*256 + lg*8;
    #pragma unroll
    for (int s = 0; s < 8; ++s) {
        const bf16x8 ah = *(const bf16x8*)(WtH + arow + s*32);
        const bf16x8 al = *(const bf16x8*)(WtL + arow + s*32);
        #pragma unroll
        for (int ni = 0; ni < 4; ++ni) {
            const int row = ni*16 + lr;
            const int slot = s*4 + lg;
            const int idx = row*256 + ((slot ^ (row & 7)) << 3);
            const bf16x8 bh_ = *(const bf16x8*)&sh[idx];
            const bf16x8 bl_ = *(const bf16x8*)&sh[16384 + idx];
            acc[ni] = __builtin_amdgcn_mfma_f32_16x16x32_bf16(ah, bh_, acc[ni], 0, 0, 0);
            acc[ni] = __builtin_amdgcn_mfma_f32_16x16x32_bf16(ah, bl_, acc[ni], 0, 0, 0);
            acc[ni] = __builtin_amdgcn_mfma_f32_16x16x32_bf16(al, bh_, acc[ni], 0, 0, 0);
        }
    }

    if constexpr (MODE == 0) {
        #pragma unroll
        for (int ni = 0; ni < 4; ++ni)
            #pragma unroll
            for (int r = 0; r < 4; ++r) {
                const int co = co0 + w*16 + lg*4 + r;
                const int nn = n0 + ni*16 + lr;
                float v = acc[ni][r];
                if (U) v += U[co*3 + d];
                OutF[(((long)(b*256 + co))*3 + d)*1024 + nn] = v;
            }
    } else if constexpr (MODE == 1) {
        #pragma unroll
        for (int ni = 0; ni < 4; ++ni)
            #pragma unroll
            for (int r = 0; r < 4; ++r) {
                const int co = co0 + w*16 + lg*4 + r;
                const int nn = n0 + ni*16 + lr;
                float v = acc[ni][r] + U[co*3 + d];
                const long idx = (((long)(b*256 + co))*3 + d)*1024 + nn;
                const u16 hi = f2bf(v);
                OutH[idx] = hi;
                OutL[idx] = f2bf(v - bf2f(hi));
            }
    } else {
        __syncthreads();
        u16* olh = sh;
        u16* oll = sh + 8448;
        #pragma unroll
        for (int ni = 0; ni < 4; ++ni)
            #pragma unroll
            for (int r = 0; r < 4; ++r) {
                const int co_l = w*16 + lg*4 + r;
                float v = acc[ni][r] + U[(co0 + co_l)*3 + d];
                const u16 hi = f2bf(v);
                olh[co_l*66 + ni*16 + lr] = hi;
                oll[co_l*66 + ni*16 + lr] = f2bf(v - bf2f(hi));
            }
        __syncthreads();
        const int n_l = tid & 63, grp = tid >> 6;
        const int h = (co0 >> 5) + (grp >> 1);
        const long base = ((long)(b*8 + h)*1024 + n0 + n_l)*96 + d*32 + (grp & 1)*16;
        u16x8 v0h, v1h, v0l, v1l;
        #pragma unroll
        for (int p = 0; p < 8; ++p) {
            v0h[p] = olh[(grp*16 + p)*66 + n_l];
            v1h[p] = olh[(grp*16 + 8 + p)*66 + n_l];
            v0l[p] = oll[(grp*16 + p)*66 + n_l];
            v1l[p] = oll[(grp*16 + 8 + p)*66 + n_l];
        }
        *(u16x8*)&OutH[base]     = v0h;
        *(u16x8*)&OutH[base + 8] = v1h;
        *(u16x8*)&OutL[base]     = v0l;
        *(u16x8*)&OutL[base + 8] = v1l;
    }
}

// ---------------------------------------------------------------- fused attention, XCD-swizzled flat grid
// q/k: [bh][n][96] hi/lo (head-major). z: [b][c][d][n] hi/lo. Ao: [b*768 + h*96 + f][m] f32.
__global__ __launch_bounds__(256) void k_attn(
    const u16* __restrict__ Qh, const u16* __restrict__ Ql,
    const u16* __restrict__ Kh, const u16* __restrict__ Kl,
    const u16* __restrict__ Zh, const u16* __restrict__ Zl,
    float* __restrict__ Ao)
{
    // XCD-aware remap: block i runs on XCD i%8; give each XCD contiguous bh's
    // so its resident blocks share K/Z (working set ~1.5MB < 4MB XCD L2).
    const int i = blockIdx.x;            // 0..4095
    const int xcd = i & 7;
    const int j = i >> 3;                // 0..511
    const int bh = xcd*8 + (j >> 6);     // 8 bh per XCD
    const int mt = j & 63;
    const int b = bh >> 3, h = bh & 7;
    const int m0 = mt*16;
    const int tid = threadIdx.x;
    const int w = tid >> 6, l = tid & 63, lr = l & 15, lg = l >> 4;

    __shared__ float S[16*1024];       // 64 KB; becomes P hi/lo (row-local) after softmax
    __shared__ float outl[16*100];
    __shared__ float inv16[16];

    f32x4 zero = {0.f, 0.f, 0.f, 0.f};

    // ---- phase 1: S[m][n] = ISQ * sum_f q[m][f]*k[n][f]   (split-bf16, 3 MFMA per pair)
    const long qbase = ((long)bh*1024 + m0 + lr)*96 + lg*8;
    bf16x8 qhf[3], qlf[3];
    #pragma unroll
    for (int s = 0; s < 3; ++s) {
        qhf[s] = *(const bf16x8*)(Qh + qbase + s*32);
        qlf[s] = *(const bf16x8*)(Ql + qbase + s*32);
    }
    for (int nf = 0; nf < 16; ++nf) {
        const int n0 = w*256 + nf*16;
        const long kb = ((long)bh*1024 + n0 + lr)*96 + lg*8;
        f32x4 acc = zero;
        #pragma unroll
        for (int s = 0; s < 3; ++s) {
            const bf16x8 khf = *(const bf16x8*)(Kh + kb + s*32);
            const bf16x8 klf = *(const bf16x8*)(Kl + kb + s*32);
            acc = __builtin_amdgcn_mfma_f32_16x16x32_bf16(qhf[s], khf, acc, 0, 0, 0);
            acc = __builtin_amdgcn_mfma_f32_16x16x32_bf16(qhf[s], klf, acc, 0, 0, 0);
            acc = __builtin_amdgcn_mfma_f32_16x16x32_bf16(qlf[s], khf, acc, 0, 0, 0);
        }
        #pragma unroll
        for (int r = 0; r < 4; ++r)
            S[(lg*4 + r)*1024 + n0 + lr] = acc[r] * ISQ;
    }
    __syncthreads();

    // ---- phase 2: softmax (row in registers; unnormalized P hi/lo back into S, row-local, swizzled)
    {
        const int r = tid >> 4, s = tid & 15;
        float preg[64];
        float mx = -1e30f;
        #pragma unroll
        for (int j2 = 0; j2 < 64; ++j2) {
            preg[j2] = S[r*1024 + j2*16 + s];
            mx = fmaxf(mx, preg[j2]);
        }
        #pragma unroll
        for (int off = 1; off < 16; off <<= 1)
            mx = fmaxf(mx, __shfl_xor(mx, off));
        float sm = 0.f;
        #pragma unroll
        for (int j2 = 0; j2 < 64; ++j2) {
            const float p = __expf(preg[j2] - mx);
            preg[j2] = p;
            sm += p;
        }
        #pragma unroll
        for (int off = 1; off < 16; off <<= 1)
            sm += __shfl_xor(sm, off);
        if (s == 0) inv16[r] = 1.0f / sm;
        __syncthreads();
        char* Sb = (char*)S;
        #pragma unroll
        for (int j2 = 0; j2 < 64; ++j2) {
            const int n = j2*16 + s;
            const u16 hi = f2bf(preg[j2]);
            const u16 lo = f2bf(preg[j2] - bf2f(hi));
            const int byoff = (n*2) ^ ((r & 7) << 4);   // swizzle within 2KB half-row
            *(u16*)(Sb + r*4096 + byoff)        = hi;
            *(u16*)(Sb + r*4096 + 2048 + byoff) = lo;
        }
    }
    __syncthreads();

    // ---- phase 3: PV partials over this wave's 256-col n-range
    f32x4 acc2[6];
    #pragma unroll
    for (int f = 0; f < 6; ++f) acc2[f] = zero;
    const long zrow = (long)(b*768 + h*96);
    const char* Sb = (const char*)S;
    for (int kb = 0; kb < 8; ++kb) {
        const int n = w*256 + kb*32 + lg*8;
        const int byoff = lr*4096 + (((n*2)) ^ ((lr & 7) << 4));
        const bf16x8 ph = *(const bf16x8*)(Sb + byoff);
        const bf16x8 pl = *(const bf16x8*)(Sb + byoff + 2048);
        #pragma unroll
        for (int ff = 0; ff < 6; ++ff) {
            const long zb = (zrow + ff*16 + lr)*1024 + n;
            const bf16x8 azh = *(const bf16x8*)(Zh + zb);
            const bf16x8 azl = *(const bf16x8*)(Zl + zb);
            acc2[ff] = __builtin_amdgcn_mfma_f32_16x16x32_bf16(ph, azh, acc2[ff], 0, 0, 0);
            acc2[ff] = __builtin_amdgcn_mfma_f32_16x16x32_bf16(ph, azl, acc2[ff], 0, 0, 0);
            acc2[ff] = __builtin_amdgcn_mfma_f32_16x16x32_bf16(pl, azh, acc2[ff], 0, 0, 0);
        }
    }
    __syncthreads();
    // staged deterministic cross-wave reduce
    for (int wv = 0; wv < 4; ++wv) {
        if (w == wv) {
            #pragma unroll
            for (int ff = 0; ff < 6; ++ff)
                #pragma unroll
                for (int r = 0; r < 4; ++r) {
                    const int m = lg*4 + r, f = ff*16 + lr;
                    if (wv == 0) outl[m*100 + f] = acc2[ff][r];
                    else         outl[m*100 + f] += acc2[ff][r];
                }
        }
        __syncthreads();
    }
    // ---- phase 4: normalized, coalesced write
    for (int idx = tid; idx < 384; idx += 256) {
        const int f = idx >> 2, mg = idx & 3;
        float4 o;
        o.x = outl[(mg*4+0)*100 + f] * inv16[mg*4+0];
        o.y = outl[(mg*4+1)*100 + f] * inv16[mg*4+1];
        o.z = outl[(mg*4+2)*100 + f] * inv16[mg*4+2];
        o.w = outl[(mg*4+3)*100 + f] * inv16[mg*4+3];
        *(float4*)&Ao[(long)(b*768 + h*96 + f)*1024 + m0 + mg*4] = o;
    }
}

// ---------------------------------------------------------------- VN LayerNorm (+residual) [r1 verbatim]
__global__ __launch_bounds__(256) void k_vnln(
    const float* __restrict__ X, const float* __restrict__ Res,
    const float* __restrict__ g, const float* __restrict__ be,
    float* __restrict__ Out)
{
    const int b  = blockIdx.x >> 5;
    const int n  = ((blockIdx.x & 31) << 5) + threadIdx.x;
    const int ty = threadIdx.y;
    const long bbase = (long)b * (256*3*1024);
    float sum = 0.0f, sq = 0.0f;
    for (int ci = 0; ci < 32; ++ci) {
        const int c = (ty << 5) + ci;
        const long base = bbase + (long)c*3072 + n;
        const float x0 = X[base], x1 = X[base+1024], x2 = X[base+2048];
        const float nr = sqrtf(x0*x0 + x1*x1 + x2*x2) + VN_EPS;
        sum += nr; sq += nr*nr;
    }
    __shared__ float s_sum[8][32], s_sq[8][32];
    s_sum[ty][threadIdx.x] = sum; s_sq[ty][threadIdx.x] = sq;
    __syncthreads();
    __shared__ float s_mu[32], s_rs[32];
    if (ty == 0) {
        float S = 0.0f, Q = 0.0f;
        #pragma unroll
        for (int w = 0; w < 8; ++w) { S += s_sum[w][threadIdx.x]; Q += s_sq[w][threadIdx.x]; }
        const float mu = S / 256.0f;
        s_mu[threadIdx.x] = mu;
        s_rs[threadIdx.x] = rsqrtf(Q / 256.0f - mu*mu + LN_EPS);
    }
    __syncthreads();
    const float mu = s_mu[threadIdx.x], rstd = s_rs[threadIdx.x];
    for (int ci = 0; ci < 32; ++ci) {
        const int c = (ty << 5) + ci;
        const long base = bbase + (long)c*3072 + n;
        const float x0 = X[base], x1 = X[base+1024], x2 = X[base+2048];
        const float nr = sqrtf(x0*x0 + x1*x1 + x2*x2) + VN_EPS;
        const float ln = (nr - mu) * rstd * g[c] + be[c];
        const float s  = ln / nr;
        float o0 = x0*s, o1 = x1*s, o2 = x2*s;
        if (Res) { o0 += Res[base]; o1 += Res[base+1024]; o2 += Res[base+2048]; }
        Out[base] = o0; Out[base+1024] = o1; Out[base+2048] = o2;
    }
}

// ---------------------------------------------------------------- BN stats [r7 verbatim]
__global__ __launch_bounds__(256) void k_bnstats(
    const float* __restrict__ X, float* __restrict__ bnst)
{
    const int c = blockIdx.x;
    const int t = threadIdx.x;
    float sum = 0.0f, sq = 0.0f;
    for (int b = 0; b < 8; ++b) {
        const long rowbase = ((long)(b*256 + c)) * 3072;
        for (int n0 = 0; n0 < 1024; n0 += 256) {
            const int n = n0 + t;
            const float x0 = X[rowbase + n], x1 = X[rowbase + 1024 + n], x2 = X[rowbase + 2048 + n];
            const float nr = sqrtf(x0*x0 + x1*x1 + x2*x2) + VN_EPS;
            sum += nr; sq += nr*nr;
        }
    }
    #pragma unroll
    for (int off = 32; off > 0; off >>= 1) {
        sum += __shfl_xor(sum, off);
        sq  += __shfl_xor(sq,  off);
    }
    __shared__ float rs[4], rq[4];
    if ((t & 63) == 0) { rs[t >> 6] = sum; rq[t >> 6] = sq; }
    __syncthreads();
    if (t == 0) {
        const float S = rs[0]+rs[1]+rs[2]+rs[3];
        const float Q = rq[0]+rq[1]+rq[2]+rq[3];
        const float mu = S / 8192.0f;
        bnst[c] = mu;
        bnst[256 + c] = rsqrtf(Q / 8192.0f - mu*mu + BN_EPS);
    }
}

// ---------------------------------------------------------------- BN apply in place [r7 verbatim]
__global__ __launch_bounds__(256) void k_bnapply(
    float* __restrict__ X, const float* __restrict__ bnst,
    const float* __restrict__ g, const float* __restrict__ be)
{
    const long i = (long)blockIdx.x * 256 + threadIdx.x;
    const int  n  = (int)(i & 1023);
    const long bc = i >> 10;
    const int  c  = (int)(bc & 255);
    const long base = bc * 3072 + n;
    const float x0 = X[base], x1 = X[base+1024], x2 = X[base+2048];
    const float nr = sqrtf(x0*x0 + x1*x1 + x2*x2) + VN_EPS;
    const float bn = (nr - bnst[c]) * bnst[256 + c] * g[c] + be[c];
    const float s  = bn / nr;
    X[base]      = x0*s;
    X[base+1024] = x1*s;
    X[base+2048] = x2*s;
}

// ---------------------------------------------------------------- VN leaky relu (slope 0) in place [r7 verbatim]
__global__ __launch_bounds__(256) void k_leaky(
    float* __restrict__ X, const float* __restrict__ Dd)
{
    const long i = (long)blockIdx.x * 256 + threadIdx.x;
    const long base = (i >> 10) * 3072 + (i & 1023);
    const float x0 = X[base], x1 = X[base+1024], x2 = X[base+2048];
    const float d0 = Dd[base], d1 = Dd[base+1024], d2 = Dd[base+2048];
    const float dot = x0*d0 + x1*d1 + x2*d2;
    if (dot < 0.0f) {
        const float f = dot / (d0*d0 + d1*d1 + d2*d2 + VN_EPS);
        X[base]      = x0 - f*d0;
        X[base+1024] = x1 - f*d1;
        X[base+2048] = x2 - f*d2;
    }
}

// ================================================================ launch
extern "C" void kernel_launch(void* const* d_in, const int* in_sizes, int n_in,
                              void* d_out, int out_size, void* d_ws, size_t ws_size,
                              hipStream_t stream)
{
    const float* x    = (const float*)d_in[0];
    const float* Wq   = (const float*)d_in[1];
    const float* bq   = (const float*)d_in[2];
    const float* Wk   = (const float*)d_in[3];
    const float* bk   = (const float*)d_in[4];
    const float* Wz   = (const float*)d_in[5];
    const float* bz   = (const float*)d_in[6];
    const float* Wo   = (const float*)d_in[7];
    const float* bo   = (const float*)d_in[8];
    const float* ln1g = (const float*)d_in[9];
    const float* ln1b = (const float*)d_in[10];
    const float* Wm1  = (const float*)d_in[11];
    const float* bm1  = (const float*)d_in[12];
    const float* bng  = (const float*)d_in[13];
    const float* bnb  = (const float*)d_in[14];
    const float* Wr   = (const float*)d_in[15];
    const float* Wm2  = (const float*)d_in[16];
    const float* bm2  = (const float*)d_in[17];
    const float* ln2g = (const float*)d_in[18];
    const float* ln2b = (const float*)d_in[19];
    float* out = (float*)d_out;

    char* wsb = (char*)d_ws;
    u16*   qh  = (u16*)(wsb + 0);
    u16*   ql  = (u16*)(wsb + 12582912);
    u16*   kh  = (u16*)(wsb + 25165824);
    u16*   kl  = (u16*)(wsb + 37748736);
    u16*   zh  = (u16*)(wsb + 50331648);
    u16*   zl  = (u16*)(wsb + 62914560);
    u16*   wth = (u16*)(wsb + 109051904);
    u16*   wtl = (u16*)(wsb + 109969408);
    float* uall= (float*)(wsb + 110886912);
    float* bnst= (float*)(wsb + 110905344);
    // phase C aliases (attention buffers dead)
    float* ao  = out;                          // d_out as attn-out scratch
    float* y0f = (float*)(wsb + 0);
    float* y   = (float*)(wsb + 25165824);
    float* h   = (float*)(wsb + 50331648);
    float* dv  = (float*)(wsb + 75497472);
    float* h2  = (float*)(wsb + 0);

    const dim3 GC(16, 4, 24);

    k_u<<<6, 256, 0, stream>>>(bq, bk, bz, bo, bm1, bm2, uall);
    k_wtrans<<<dim3(4,4,7), 256, 0, stream>>>(Wq, Wk, Wz, Wo, Wm1, Wr, Wm2, wth, wtl);

    // projections
    k_cgemm<2><<<GC, 256, 0, stream>>>(x, wth + 0*65536, wtl + 0*65536, uall + 0*768, nullptr, qh, ql);
    k_cgemm<2><<<GC, 256, 0, stream>>>(x, wth + 1*65536, wtl + 1*65536, uall + 1*768, nullptr, kh, kl);
    k_cgemm<1><<<GC, 256, 0, stream>>>(x, wth + 2*65536, wtl + 2*65536, uall + 2*768, nullptr, zh, zl);

    // fused attention (flat grid, XCD-swizzled inside)
    k_attn<<<4096, 256, 0, stream>>>(qh, ql, kh, kl, zh, zl, ao);

    // out projection + LN1 (+ residual x)
    k_cgemm<0><<<GC, 256, 0, stream>>>(ao, wth + 3*65536, wtl + 3*65536, uall + 3*768, y0f, nullptr, nullptr);
    k_vnln<<<256, dim3(32,8), 0, stream>>>(y0f, x, ln1g, ln1b, y);

    // MLP
    k_cgemm<0><<<GC, 256, 0, stream>>>(y, wth + 4*65536, wtl + 4*65536, uall + 4*768, h, nullptr, nullptr);
    k_bnstats<<<256, 256, 0, stream>>>(h, bnst);
    k_bnapply<<<8192, 256, 0, stream>>>(h, bnst, bng, bnb);
    k_cgemm<0><<<GC, 256, 0, stream>>>(h, wth + 5*65536, wtl + 5*65536, (const float*)nullptr, dv, nullptr, nullptr);
    k_leaky<<<8192, 256, 0, stream>>>(h, dv);
    k_cgemm<0><<<GC, 256, 0, stream>>>(h, wth + 6*65536, wtl + 6*65536, uall + 5*768, h2, nullptr, nullptr);
    k_vnln<<<256, dim3(32,8), 0, stream>>>(h2, y, ln2g, ln2b, out);
}